// Round 1
// 46.029 us; speedup vs baseline: 2.0604x; 2.0604x over previous
//
#include <hip/hip_runtime.h>

#define N_BOX 5376
#define NQ4   1344          // N_BOX/4
#define NCAND 1024
#define MAXD  300
#define NTH   1024
#define NPRE  320           // candidates covered by precomputed pairwise masks
#define NPREB 5             // NPRE/64
#define RANK_TGT 768
#define FLOOR_B 2000        // bucket(0.25f)
#define SCORE_T 0.25f

typedef unsigned long long u64;
typedef unsigned int u32;
typedef unsigned short u16;

// monotone score->bucket map, fine resolution in [0.5, 1)
__device__ __forceinline__ int bucket_of(u32 u) {
    if (u >= 0x3F800000u) return 4095;
    return (u < 0x3F000000u) ? (int)(u >> 19) : 2016 + (int)((u - 0x3F000000u) >> 12);
}

__global__ __launch_bounds__(NTH) void k_nms(
        const float* __restrict__ boxes, float* __restrict__ out,
        int* __restrict__ sel_orig, float4* __restrict__ rrcc)
{
    __shared__ int hist[4096];                       // counts -> (in place) suffix bases
    __shared__ u16 basecopy[4096];                   // segment starts for stabilization
    __shared__ u64 keys[NCAND];
    __shared__ __align__(16) float4 cbox[NCAND];     // scatter-order coords
    __shared__ __align__(16) float4 selbox[MAXD];    // selected boxes (y1,x1,y2,x2)
    __shared__ __align__(16) float4 batchb[64];      // current batch boxes (fallback path)
    __shared__ __align__(16) u32 svals[N_BOX];       // cached score bits
    __shared__ u32 sclsp[NQ4];                       // 4x packed cls per float4 group
    __shared__ __align__(16) float4 scbox[NPRE];     // sorted-order boxes (first NPRE)
    __shared__ float sarea[NPRE];                    // matching areas
    __shared__ u64 supr[NPREB][NPRE];                // pairwise overlap bitmasks, word-major
    __shared__ u64 selw[NPREB];                      // selected-lane mask per batch
    __shared__ int thrvar, ncvar, scnt;
    const int tid = threadIdx.x;

    // P0: zero
    for (int b = tid; b < 4096; b += NTH) hist[b] = 0;
    for (int i = tid; i < NCAND; i += NTH) keys[i] = 0;
    if (tid == 0) { thrvar = FLOOR_B; ncvar = 0; }
    __syncthreads();

    // P1: vectorized score+cls compute, cache in LDS, histogram
    {
        const float4* r4 = (const float4*)(boxes + 4 * N_BOX);
        const float4* r5 = (const float4*)(boxes + 5 * N_BOX);
        const float4* r6 = (const float4*)(boxes + 6 * N_BOX);
        const float4* r7 = (const float4*)(boxes + 7 * N_BOX);
        for (int t = tid; t < NQ4; t += NTH) {
            float4 a = r4[t], b = r5[t], c = r6[t], d = r7[t];
            uint4 sv; u32 pk; float s; int cl;
            s = a.x; cl = 0;
            if (b.x > s) { s = b.x; cl = 1; }
            if (c.x > s) { s = c.x; cl = 2; }
            if (d.x > s) { s = d.x; cl = 3; }
            sv.x = __float_as_uint(s); pk = (u32)cl;
            s = a.y; cl = 0;
            if (b.y > s) { s = b.y; cl = 1; }
            if (c.y > s) { s = c.y; cl = 2; }
            if (d.y > s) { s = d.y; cl = 3; }
            sv.y = __float_as_uint(s); pk |= (u32)cl << 8;
            s = a.z; cl = 0;
            if (b.z > s) { s = b.z; cl = 1; }
            if (c.z > s) { s = c.z; cl = 2; }
            if (d.z > s) { s = d.z; cl = 3; }
            sv.z = __float_as_uint(s); pk |= (u32)cl << 16;
            s = a.w; cl = 0;
            if (b.w > s) { s = b.w; cl = 1; }
            if (c.w > s) { s = c.w; cl = 2; }
            if (d.w > s) { s = d.w; cl = 3; }
            sv.w = __float_as_uint(s); pk |= (u32)cl << 24;
            ((uint4*)svals)[t] = sv;
            sclsp[t] = pk;
            atomicAdd(&hist[bucket_of(sv.x)], 1);
            atomicAdd(&hist[bucket_of(sv.y)], 1);
            atomicAdd(&hist[bucket_of(sv.z)], 1);
            atomicAdd(&hist[bucket_of(sv.w)], 1);
        }
    }
    __syncthreads();

    // P2+P3 (wave 0): find threshold bucket, then in-place suffix scan hist->base
    if (tid < 64) {
        const int lane = tid;
        int csum = 0;
        for (int b = lane * 64; b < lane * 64 + 64; ++b) csum += hist[b];
        int incl = csum;                              // suffix-inclusive over chunks
        for (int off = 1; off < 64; off <<= 1) {
            int t = __shfl_down(incl, off);
            if (lane + off < 64) incl += t;
        }
        int excl = __shfl_down(incl, 1);
        if (lane == 63) excl = 0;
        if (incl >= RANK_TGT && excl < RANK_TGT) {    // at most one lane
            int cum = excl, thr = FLOOR_B;
            for (int b = lane * 64 + 63; b >= lane * 64; --b) {
                cum += hist[b];
                if (cum >= RANK_TGT) { thr = b; break; }
            }
            thrvar = (thr > FLOOR_B) ? thr : FLOOR_B;
        }
        int thr = thrvar;                             // wave-internal LDS broadcast
        int run = excl;
        for (int b = lane * 64 + 63; b >= lane * 64; --b) {
            int h = hist[b];
            hist[b] = run;                            // base (read h first)
            basecopy[b] = (u16)run;
            if (b == thr) { int v = run + h; ncvar = (v < NCAND) ? v : NCAND; }
            run += h;
        }
    }
    __syncthreads();
    const int thr = thrvar;

    // P4: scatter candidates to bucket segments; coords (vectorized) to segment slots
    {
        const float4* r0 = (const float4*)(boxes);
        const float4* r1 = (const float4*)(boxes + 1 * N_BOX);
        const float4* r2 = (const float4*)(boxes + 2 * N_BOX);
        const float4* r3 = (const float4*)(boxes + 3 * N_BOX);
        for (int t = tid; t < NQ4; t += NTH) {
            uint4 sv = ((const uint4*)svals)[t];
            int b0 = bucket_of(sv.x), b1 = bucket_of(sv.y),
                b2 = bucket_of(sv.z), b3 = bucket_of(sv.w);
            int bm = max(max(b0, b1), max(b2, b3));
            if (bm < thr) continue;
            float4 xs = r0[t], ys = r1[t], ws = r2[t], hs = r3[t];
            u32 pk = sclsp[t];
            int n = t << 2;
            if (b0 >= thr) {
                int pos = atomicAdd(&hist[b0], 1);
                if (pos < NCAND) {
                    cbox[pos] = make_float4(ys.x - 0.5f * hs.x, xs.x - 0.5f * ws.x,
                                            ys.x + 0.5f * hs.x, xs.x + 0.5f * ws.x);
                    keys[pos] = ((u64)sv.x << 25) | ((u64)(8191 - n) << 12)
                              | ((u64)(pk & 3u) << 10) | (u64)pos;
                }
            }
            if (b1 >= thr) {
                int pos = atomicAdd(&hist[b1], 1);
                if (pos < NCAND) {
                    cbox[pos] = make_float4(ys.y - 0.5f * hs.y, xs.y - 0.5f * ws.y,
                                            ys.y + 0.5f * hs.y, xs.y + 0.5f * ws.y);
                    keys[pos] = ((u64)sv.y << 25) | ((u64)(8191 - (n + 1)) << 12)
                              | ((u64)((pk >> 8) & 3u) << 10) | (u64)pos;
                }
            }
            if (b2 >= thr) {
                int pos = atomicAdd(&hist[b2], 1);
                if (pos < NCAND) {
                    cbox[pos] = make_float4(ys.z - 0.5f * hs.z, xs.z - 0.5f * ws.z,
                                            ys.z + 0.5f * hs.z, xs.z + 0.5f * ws.z);
                    keys[pos] = ((u64)sv.z << 25) | ((u64)(8191 - (n + 2)) << 12)
                              | ((u64)((pk >> 16) & 3u) << 10) | (u64)pos;
                }
            }
            if (b3 >= thr) {
                int pos = atomicAdd(&hist[b3], 1);
                if (pos < NCAND) {
                    cbox[pos] = make_float4(ys.w - 0.5f * hs.w, xs.w - 0.5f * ws.w,
                                            ys.w + 0.5f * hs.w, xs.w + 0.5f * ws.w);
                    keys[pos] = ((u64)sv.w << 25) | ((u64)(8191 - (n + 3)) << 12)
                              | ((u64)((pk >> 24) & 3u) << 10) | (u64)pos;
                }
            }
        }
    }
    __syncthreads();
    const int nc = ncvar;

    // P5: stabilize each bucket segment by exact-rank rewrite (deterministic)
    {
        u64 myk[2]; int mypos[2]; int cnt = 0;
        for (int p = tid; p < nc; p += NTH) {
            u64 kp = keys[p];
            int b = bucket_of((u32)(kp >> 25));
            int start = (int)basecopy[b];
            int end = hist[b]; if (end > NCAND) end = NCAND;
            int rank = 0;
            for (int q = start; q < end; ++q) rank += (keys[q] > kp);
            myk[cnt] = kp; mypos[cnt] = start + rank; ++cnt;
        }
        __syncthreads();
        for (int i = 0; i < cnt; ++i) keys[mypos[i]] = myk[i];
    }
    __syncthreads();

    // P5b: build sorted-order box/area tables for first NPRE candidates
    {
        const int lim = (nc < NPRE) ? nc : NPRE;
        for (int c = tid; c < NPRE; c += NTH) {
            float4 bx = make_float4(0.f, 0.f, 0.f, 0.f);
            if (c < lim) bx = cbox[(int)(keys[c] & 0x3FFu)];
            scbox[c] = bx;
            sarea[c] = (bx.z - bx.x) * (bx.w - bx.y);
        }
    }
    __syncthreads();

    // P5c: pairwise overlap bitmasks for first NPRE candidates (all waves parallel)
    //      supr[w][c] bit q == candidate (64w+q) overlaps candidate c (IoU > T)
    {
        const int wav = tid >> 6, lane = tid & 63;
        for (int t = wav; t < 15; t += NTH / 64) {    // lower-triangle chunks only
            int w, cb;
            if (t < 5)       { w = 0; cb = t << 6; }
            else if (t < 9)  { w = 1; cb = (t - 4) << 6; }
            else if (t < 12) { w = 2; cb = (t - 7) << 6; }
            else if (t < 14) { w = 3; cb = (t - 9) << 6; }
            else             { w = 4; cb = 256; }
            float4 qb = scbox[(w << 6) + lane];       // lane-owned column box
            float qa = sarea[(w << 6) + lane];
            for (int c = cb; c < cb + 64; ++c) {
                float4 bx = scbox[c];                 // broadcast row box
                float ar = sarea[c];
                float iy1 = fmaxf(bx.x, qb.x), ix1 = fmaxf(bx.y, qb.y);
                float iy2 = fminf(bx.z, qb.z), ix2 = fminf(bx.w, qb.w);
                float inter = fmaxf(iy2 - iy1, 0.f) * fmaxf(ix2 - ix1, 0.f);
                bool h = (1.75f * inter > 0.75f * (ar + qa) + 7.5e-10f);
                u64 m = __ballot(h);
                if (lane == 0) supr[w][c] = m;
            }
        }
    }
    __syncthreads();

    // P6 (wave 0): batch-parallel greedy NMS, 64 candidates per round.
    // Batches fully inside NPRE use precomputed masks; beyond -> exact old path.
    if (tid < 64) {
        const int lane = tid;
        const u64 laneb = 1ull << lane;
        int scount = 0;
        for (int base = 0; base < nc; base += 64) {
            const int bidx = base >> 6;
            const bool pre = (base + 64 <= NPRE);
            int idx = base + lane;
            u64 k = 0;
            if (idx < nc) k = keys[idx];
            float sc = __uint_as_float((u32)(k >> 25));
            bool valid = (idx < nc) && (sc >= SCORE_T);
            float4 bx = make_float4(0.f, 0.f, 0.f, 0.f);
            bool dead = false;
            u64 M = 0;
            if (pre) {
                if (valid) bx = scbox[idx];
                #pragma unroll
                for (int w = 0; w < NPREB; ++w)
                    if (w < bidx)
                        dead = dead || ((supr[w][idx] & selw[w]) != 0ull);
                M = supr[bidx][idx] & (laneb - 1ull);
            } else {
                if (valid) bx = cbox[(int)(k & 0x3FFu)];
                batchb[lane] = bx;
                float ar = (bx.z - bx.x) * (bx.w - bx.y);

                // vs already-selected list (uniform broadcast reads, pipelined)
                #pragma unroll 4
                for (int j = 0; j < scount; ++j) {
                    float4 sb = selbox[j];
                    float sar = (sb.z - sb.x) * (sb.w - sb.y);
                    float iy1 = fmaxf(bx.x, sb.x), ix1 = fmaxf(bx.y, sb.y);
                    float iy2 = fminf(bx.z, sb.z), ix2 = fminf(bx.w, sb.w);
                    float inter = fmaxf(iy2 - iy1, 0.f) * fmaxf(ix2 - ix1, 0.f);
                    dead = dead || (1.75f * inter > 0.75f * (ar + sar) + 7.5e-10f);
                }

                // intra-batch suppression rows
                #pragma unroll 4
                for (int q = 0; q < 64; ++q) {
                    float4 sb = batchb[q];
                    float sar = (sb.z - sb.x) * (sb.w - sb.y);
                    float iy1 = fmaxf(bx.x, sb.x), ix1 = fmaxf(bx.y, sb.y);
                    float iy2 = fminf(bx.z, sb.z), ix2 = fminf(bx.w, sb.w);
                    float inter = fmaxf(iy2 - iy1, 0.f) * fmaxf(ix2 - ix1, 0.f);
                    bool h = (1.75f * inter > 0.75f * (ar + sar) + 7.5e-10f) && (q < lane);
                    if (h) M |= (1ull << q);
                }
            }

            u64 vmask  = __ballot(valid);
            u64 deadm  = __ballot(dead);
            u64 alive0 = vmask & ~deadm;
            u64 sel    = alive0;
            u64 conf   = __ballot((M & alive0) != 0ull) & alive0;
            while (conf) {                            // rare: ~0.5 conflicts/batch
                int f = (int)__ffsll((unsigned long long)conf) - 1;
                conf &= conf - 1ull;
                u64 Mf = ((u64)(u32)__shfl((int)(M >> 32), f) << 32)
                       | (u64)(u32)__shfl((int)(M & 0xFFFFFFFFull), f);
                if (Mf & sel) sel &= ~(1ull << f);    // f suppressed by a final keeper
            }
            if (pre && lane == 0) selw[bidx] = sel;

            int navail = MAXD - scount;
            int myrank = (int)__popcll(sel & (laneb - 1ull));
            bool chosen = ((sel & laneb) != 0ull) && (myrank < navail);
            if (chosen) {
                int slot = scount + myrank;
                selbox[slot] = bx;
                out[slot]        = sc;
                out[MAXD + slot] = (float)((k >> 10) & 3u);
                ((float4*)(out + 2 * MAXD))[slot] = bx;
                sel_orig[slot] = 8191 - (int)((k >> 12) & 0x1FFFu);
                rrcc[slot] = make_float4(0.25f * bx.x, 0.25f * bx.z,
                                         0.25f * bx.y, 0.25f * bx.w);
            }
            int nsel = (int)__popcll(sel);
            if (nsel > navail) nsel = navail;
            scount += nsel;
            if (scount >= MAXD) break;                // cap reached
            if (vmask != 0xFFFFFFFFFFFFFFFFull) break; // tail batch
        }
        if (lane == 0) scnt = scount;
    }
    __syncthreads();

    // P7: fill remaining slots
    const int c0f = scnt;
    for (int s = c0f + tid; s < MAXD; s += NTH) {
        out[s] = 0.f; out[MAXD + s] = 0.f;
        ((float4*)(out + 2 * MAXD))[s] = make_float4(0.f, 0.f, 0.f, 0.f);
        sel_orig[s] = -1;
        rrcc[s] = make_float4(1.f, 0.f, 1.f, 0.f);    // empty ranges
    }
}

// 128 blocks x 128 threads: one pixel per thread, row-filtered detection list.
__global__ __launch_bounds__(128) void k_mask(
        const float* __restrict__ boxes, const float* __restrict__ proto,
        const int* __restrict__ sel_orig, const float4* __restrict__ rrcc,
        float* __restrict__ out)
{
    __shared__ float sco[MAXD * 32];
    __shared__ float2 rl_c[MAXD];
    __shared__ int rl_k[MAXD];
    __shared__ int rcount;
    const int c = threadIdx.x, r = blockIdx.x;
    const float rf = (float)r, cf = (float)c;

    if (c < 64) {                                     // wave 0: ordered row filter
        int base = 0;
        for (int strip = 0; strip < 5; ++strip) {
            int k = strip * 64 + c;
            bool flag = false; float4 rc = make_float4(1.f, 0.f, 1.f, 0.f);
            if (k < MAXD) {
                rc = rrcc[k];
                flag = (rc.x <= rf) && (rf <= rc.y);
            }
            u64 m = __ballot(flag);
            int pos = base + (int)__popcll(m & ((1ull << c) - 1ull));
            if (flag) { rl_c[pos] = make_float2(rc.z, rc.w); rl_k[pos] = k; }
            base += (int)__popcll(m);
        }
        if (c == 0) rcount = base;
    }
    __syncthreads();
    const int L = rcount;

    for (int t = c; t < L * 32; t += 128) {           // stage surviving coeffs only
        int e = t >> 5, j = t & 31;
        sco[t] = boxes[(8 + j) * N_BOX + sel_orig[rl_k[e]]];
    }
    __syncthreads();

    const float4* q = (const float4*)(proto + (((size_t)(r << 7) + c) << 5));
    float pr[32];
    #pragma unroll
    for (int j = 0; j < 8; ++j) {
        float4 v = q[j];
        pr[4 * j + 0] = v.x; pr[4 * j + 1] = v.y;
        pr[4 * j + 2] = v.z; pr[4 * j + 3] = v.w;
    }
    float acc = 0.f;
    for (int e = 0; e < L; ++e) {
        float2 cc = rl_c[e];
        if (cc.x <= cf && cf <= cc.y) {
            const float* wv = &sco[e << 5];
            float d = 0.f;
            #pragma unroll
            for (int j = 0; j < 32; ++j) d = fmaf(pr[j], wv[j], d);
            float sg = 1.f / (1.f + __expf(-d));
            if (sg >= 0.5f) acc += sg;
        }
    }
    out[6 * MAXD + (r << 7) + c] = acc;
}

extern "C" void kernel_launch(void* const* d_in, const int* in_sizes, int n_in,
                              void* d_out, int out_size, void* d_ws, size_t ws_size,
                              hipStream_t stream) {
    const float* boxes = (const float*)d_in[0];   // (40, 5376) f32, channel-major
    const float* proto = (const float*)d_in[1];   // (128,128,32) f32
    float* out = (float*)d_out;                   // 300 + 300 + 1200 + 16384 f32

    char* w = (char*)d_ws;
    float4* rrcc = (float4*)w;
    int* sel_orig = (int*)(w + MAXD * sizeof(float4));

    hipLaunchKernelGGL(k_nms, dim3(1), dim3(NTH), 0, stream,
                       boxes, out, sel_orig, rrcc);
    hipLaunchKernelGGL(k_mask, dim3(128), dim3(128), 0, stream,
                       boxes, proto, sel_orig, rrcc, out);
}